// Round 9
// baseline (915.864 us; speedup 1.0000x reference)
//
#include <hip/hip_runtime.h>
#include <hip/hip_bf16.h>

// B=128, T=512, I=128, H=256, O=1 (fp32 in/out)
// xp = C*(x @ W_ih^T + b_ih + b_hh)   (C = 2*log2e, pre-scaled for tanh; fp32 ws)
// h_t = tanh(xp_t + h @ W_hh^T)  via MFMA, W_hh pre-scaled by C at frag load
// out = sigmoid(h_T @ W_fc^T + b_fc)
// rnn: barrier-free — per-group (16-batch) flag sync so the two groups' pipeline
// phases drift and overlap on the shared SIMD/LDS/VALU pipes.

#define B_ 128
#define T_ 512
#define I_ 128
#define H_ 256
#define HP 264   // padded LDS row stride (shorts)
#define CSCALE 2.8853900817779268f

typedef __attribute__((ext_vector_type(8))) short short8;
typedef __attribute__((ext_vector_type(4))) float floatx4;

// tanh with PRE-SCALED input x = 2*log2e*z: tanh(z) = 1 - 2*rcp(2^x + 1)
__device__ __forceinline__ float tanh_pre(float x) {
    float e = __builtin_amdgcn_exp2f(x);
    float r = __builtin_amdgcn_rcpf(e + 1.0f);
    return __builtin_fmaf(-2.0f, r, 1.0f);
}
__device__ __forceinline__ short f2bf(float f) {
    unsigned u = __float_as_uint(f);
    return (short)((u + 0x7FFFu + ((u >> 16) & 1u)) >> 16);
}
// pack two fp32 -> bf16x2: round-to-nearest (ties away), 3 insts via v_perm
__device__ __forceinline__ unsigned rn_pack(float a, float b) {
    unsigned ua = __float_as_uint(a) + 0x8000u;
    unsigned ub = __float_as_uint(b) + 0x8000u;
    return __builtin_amdgcn_perm(ub, ua, 0x07060302u);  // [ub.hi16 : ua.hi16]
}

// ---------------- Kernel A: xp[m][n] = C*(bias + x@W^T), bf16 MFMA, fp32 out.
// Tile 64m x 128n, 4 waves, ~150 VGPR -> 2 blocks/CU. (round-5 proven)
__global__ __launch_bounds__(256, 2)
void xp_mfma_kernel(const float* __restrict__ x, const float* __restrict__ W_ih,
                    const float* __restrict__ b_ih, const float* __restrict__ b_hh,
                    float* __restrict__ xp) {
    const int tid  = threadIdx.x;
    const int wave = tid >> 6, lane = tid & 63;
    const int l15  = lane & 15, quad = lane >> 4;
    const long m0 = (long)blockIdx.x * 64 + (wave & 1) * 32;
    const int  n0 = blockIdx.y * 128 + (wave >> 1) * 64;

    short8 bfrag[4][4];
#pragma unroll
    for (int nt = 0; nt < 4; ++nt)
#pragma unroll
        for (int kq = 0; kq < 4; ++kq) {
            const float* p = W_ih + (long)(n0 + nt * 16 + l15) * I_ + kq * 32 + quad * 8;
            float4 lo = *(const float4*)(p);
            float4 hi = *(const float4*)(p + 4);
            short8 f;
            f[0] = f2bf(lo.x * CSCALE); f[1] = f2bf(lo.y * CSCALE);
            f[2] = f2bf(lo.z * CSCALE); f[3] = f2bf(lo.w * CSCALE);
            f[4] = f2bf(hi.x * CSCALE); f[5] = f2bf(hi.y * CSCALE);
            f[6] = f2bf(hi.z * CSCALE); f[7] = f2bf(hi.w * CSCALE);
            bfrag[nt][kq] = f;
        }
    short8 afrag[2][4];
#pragma unroll
    for (int mt = 0; mt < 2; ++mt)
#pragma unroll
        for (int kq = 0; kq < 4; ++kq) {
            const float* p = x + (m0 + mt * 16 + l15) * I_ + kq * 32 + quad * 8;
            float4 lo = *(const float4*)(p);
            float4 hi = *(const float4*)(p + 4);
            short8 f;
            f[0] = f2bf(lo.x); f[1] = f2bf(lo.y); f[2] = f2bf(lo.z); f[3] = f2bf(lo.w);
            f[4] = f2bf(hi.x); f[5] = f2bf(hi.y); f[6] = f2bf(hi.z); f[7] = f2bf(hi.w);
            afrag[mt][kq] = f;
        }
    floatx4 acc[2][4];
#pragma unroll
    for (int mt = 0; mt < 2; ++mt)
#pragma unroll
        for (int nt = 0; nt < 4; ++nt) acc[mt][nt] = (floatx4){0.f, 0.f, 0.f, 0.f};
#pragma unroll
    for (int kq = 0; kq < 4; ++kq)
#pragma unroll
        for (int mt = 0; mt < 2; ++mt)
#pragma unroll
            for (int nt = 0; nt < 4; ++nt)
                acc[mt][nt] = __builtin_amdgcn_mfma_f32_16x16x32_bf16(
                    afrag[mt][kq], bfrag[nt][kq], acc[mt][nt], 0, 0, 0);
    float biasv[4];
#pragma unroll
    for (int nt = 0; nt < 4; ++nt) {
        int n = n0 + nt * 16 + l15;
        biasv[nt] = (b_ih[n] + b_hh[n]) * CSCALE;
    }
#pragma unroll
    for (int mt = 0; mt < 2; ++mt)
#pragma unroll
        for (int nt = 0; nt < 4; ++nt)
#pragma unroll
            for (int r = 0; r < 4; ++r) {
                long row = m0 + mt * 16 + quad * 4 + r;
                xp[row * H_ + n0 + nt * 16 + l15] = acc[mt][nt][r] + biasv[nt];
            }
}

// ---------------- Kernel B: MFMA recurrence, barrier-free flag sync.
// 4 blocks x 32 batches x 512 thr; 2 independent 16-batch groups per block.
// Protocol (per group, 4 waves):
//   reader step t:  wait wdone[w] >= t (h_t written) -> ds_read hfrags ->
//                   release rdone[wg] = t+1
//   writer step t:  wait rdone[w] >= t (h_{t-1} reads done; buffer free) ->
//                   ds_write h_{t+1} -> release wdone[wg] = t+1
// Waves within a group drift <=1 step; groups drift freely -> phase overlap.
__global__ __launch_bounds__(512, 2)
void rnn_kernel(const float* __restrict__ xp, const float* __restrict__ W_hh,
                const float* __restrict__ W_fc, const float* __restrict__ b_fc,
                float* __restrict__ out) {
    __shared__ __align__(16) short hbuf[2][2][16][HP];  // [group][parity][batch][col]
    __shared__ __align__(16) int wdone[2][4];
    __shared__ __align__(16) int rdone[2][4];
    const int tid  = threadIdx.x;
    const int wave = tid >> 6, lane = tid & 63;
    const int l15  = lane & 15, quad = lane >> 4;
    const int g    = wave >> 2;          // batch-group 0/1
    const int wg   = wave & 3;           // wave-in-group
    const int n0   = wg * 64;
    const int b0   = blockIdx.x * 32;

    // W_hh A-fragments, pre-scaled by C, resident (128 VGPR — proven pattern)
    short8 wfrag[4][8];
#pragma unroll
    for (int mt = 0; mt < 4; ++mt)
#pragma unroll
        for (int kq = 0; kq < 8; ++kq) {
            const float* p = W_hh + (long)(n0 + mt * 16 + l15) * H_ + kq * 32 + quad * 8;
            float4 lo = *(const float4*)(p);
            float4 hi = *(const float4*)(p + 4);
            short8 f;
            f[0] = f2bf(lo.x * CSCALE); f[1] = f2bf(lo.y * CSCALE);
            f[2] = f2bf(lo.z * CSCALE); f[3] = f2bf(lo.w * CSCALE);
            f[4] = f2bf(hi.x * CSCALE); f[5] = f2bf(hi.y * CSCALE);
            f[6] = f2bf(hi.z * CSCALE); f[7] = f2bf(hi.w * CSCALE);
            wfrag[mt][kq] = f;
        }

    {   // h_0 = 0, flags = 0
        int* hz = (int*)hbuf;
#pragma unroll 1
        for (int i = tid; i < (int)(sizeof(hbuf) / 4); i += 512) hz[i] = 0;
        if (tid < 4) { wdone[0][tid] = 0; wdone[1][tid] = 0;
                       rdone[0][tid] = 0; rdone[1][tid] = 0; }
    }
    __syncthreads();   // the only block-wide barrier (init)

    const float* xpl = xp + (long)(b0 + g * 16 + l15) * T_ * H_ + n0 + quad * 4;
    float4 xv[4];
#pragma unroll
    for (int mt = 0; mt < 4; ++mt) xv[mt] = *(const float4*)(xpl + mt * 16);

    const int laneoff = l15 * HP + quad * 8;
    volatile int* wd = &wdone[g][0];
    volatile int* rd = &rdone[g][0];

#pragma unroll 1
    for (int t = 0; t < T_; ++t) {
        // --- wait until h_t fully written (t=0: trivially satisfied) ---
        for (;;) {
            int f0 = wd[0], f1 = wd[1], f2 = wd[2], f3 = wd[3];
            if (min(min(f0, f1), min(f2, f3)) >= t) break;
            __builtin_amdgcn_s_sleep(1);
        }

        const short* hbr = &hbuf[g][t & 1][0][0];
        short8 hfrag[8];
#pragma unroll
        for (int kq = 0; kq < 8; ++kq)
            hfrag[kq] = *(const short8*)(hbr + laneoff + kq * 32);

        // signal: this wave's reads of h_t complete (release drains ds_reads)
        if (lane == 0)
            __hip_atomic_store(&rdone[g][wg], t + 1, __ATOMIC_RELEASE,
                               __HIP_MEMORY_SCOPE_WORKGROUP);

        floatx4 acc[4];
#pragma unroll
        for (int mt = 0; mt < 4; ++mt) {
            acc[mt][0] = xv[mt].x; acc[mt][1] = xv[mt].y;
            acc[mt][2] = xv[mt].z; acc[mt][3] = xv[mt].w;
        }
        const int tn = (t + 1) - ((t + 1) >> 9);   // clamp 512 -> 511, scalar ops
#pragma unroll
        for (int mt = 0; mt < 4; ++mt)
            xv[mt] = *(const float4*)(xpl + (long)tn * H_ + mt * 16);

#pragma unroll
        for (int kq = 0; kq < 8; ++kq)
#pragma unroll
            for (int mt = 0; mt < 4; ++mt)
                acc[mt] = __builtin_amdgcn_mfma_f32_16x16x32_bf16(
                    wfrag[mt][kq], hfrag[kq], acc[mt], 0, 0, 0);

        // --- wait until all waves done READING h_{t-1} (buffer we overwrite) ---
        for (;;) {
            int f0 = rd[0], f1 = rd[1], f2 = rd[2], f3 = rd[3];
            if (min(min(f0, f1), min(f2, f3)) >= t) break;
            __builtin_amdgcn_s_sleep(1);
        }

        short* wbp = &hbuf[g][(t + 1) & 1][0][0];
#pragma unroll
        for (int mt = 0; mt < 4; ++mt) {
            float y0 = tanh_pre(acc[mt][0]);
            float y1 = tanh_pre(acc[mt][1]);
            float y2 = tanh_pre(acc[mt][2]);
            float y3 = tanh_pre(acc[mt][3]);
            uint2 pk;
            pk.x = rn_pack(y0, y1);
            pk.y = rn_pack(y2, y3);
            *(uint2*)(wbp + l15 * HP + n0 + mt * 16 + quad * 4) = pk;
        }
        // signal: h_{t+1} chunk written (release drains ds_writes)
        if (lane == 0)
            __hip_atomic_store(&wdone[g][wg], t + 1, __ATOMIC_RELEASE,
                               __HIP_MEMORY_SCOPE_WORKGROUP);
    }

    // wait for h_T (parity 0, T even) then group-local head
    for (;;) {
        int f0 = wd[0], f1 = wd[1], f2 = wd[2], f3 = wd[3];
        if (min(min(f0, f1), min(f2, f3)) >= T_) break;
        __builtin_amdgcn_s_sleep(1);
    }
    const int lt = tid & 255;            // thread index within group
    const int bl = lt >> 4, seg = lt & 15;
    const short* hr = &hbuf[g][0][bl][seg * 16];
    float p = 0.0f;
#pragma unroll
    for (int i = 0; i < 16; ++i) {
        unsigned u = (unsigned)(unsigned short)hr[i];
        p += __uint_as_float(u << 16) * W_fc[seg * 16 + i];
    }
#pragma unroll
    for (int off = 1; off < 16; off <<= 1) p += __shfl_xor(p, off);
    if (seg == 0) out[b0 + g * 16 + bl] = 1.0f / (1.0f + __expf(-(p + b_fc[0])));
}

extern "C" void kernel_launch(void* const* d_in, const int* in_sizes, int n_in,
                              void* d_out, int out_size, void* d_ws, size_t ws_size,
                              hipStream_t stream) {
    const float* x    = (const float*)d_in[0];
    const float* W_ih = (const float*)d_in[1];
    const float* W_hh = (const float*)d_in[2];
    const float* b_ih = (const float*)d_in[3];
    const float* b_hh = (const float*)d_in[4];
    const float* W_fc = (const float*)d_in[5];
    const float* b_fc = (const float*)d_in[6];
    float* out = (float*)d_out;

    float* xp = (float*)d_ws;   // B*T*H fp32 = 67.1 MB

    dim3 gridA((B_ * T_) / 64, H_ / 128);
    xp_mfma_kernel<<<gridA, 256, 0, stream>>>(x, W_ih, b_ih, b_hh, xp);
    rnn_kernel<<<B_ / 32, 512, 0, stream>>>(xp, W_hh, W_fc, b_fc, out);
}